// Round 12
// baseline (236.302 us; speedup 1.0000x reference)
//
#include <hip/hip_runtime.h>

#define K_DIM 4096
#define M_DIM 12288
#define KW 1024             // packed int32 words per weight row
#define NT_K 32             // K-tiles of 128 bytes
#define BM 256
#define BN 256
#define GN 16               // 4096/256 token tiles
#define GM 48               // 12288/256 weight tiles

typedef __attribute__((ext_vector_type(4))) int i32x4;
typedef __attribute__((ext_vector_type(16))) int i32x16;
typedef __attribute__((ext_vector_type(4))) unsigned int u32x4;
typedef __attribute__((ext_vector_type(4))) float f32x4;

__device__ __forceinline__ int quant1(float v, float qs) {
  float r = rintf(v * qs);  // round half-to-even, matches jnp.round
  r = fminf(127.f, fmaxf(-128.f, r));
  return (int)r;
}

// unpack one packed byte into 4 code bytes (0..3) at permuted positions
__device__ __forceinline__ unsigned int unp(unsigned int uv) {
  return ((uv >> 6) | (uv << 4) | (uv << 14) | (uv << 24)) & 0x03030303u;
}

// Fused aux kernel (identical to round-7..11 passing version).
__global__ __launch_bounds__(256) void aux_kernel(const float* __restrict__ x,
                                                  const int* __restrict__ wp,
                                                  u32x4* __restrict__ xq2,
                                                  u32x4* __restrict__ wu2,
                                                  float2* __restrict__ scales) {
  __shared__ float redf[4];
  __shared__ int redi[4];
  __shared__ u32x4 ldsT[32][9];  // padded: 8-lane groups conflict-free both phases
  const int t = threadIdx.x;

  if (blockIdx.x < 4096) {
    // ---------------- quant path: one block per token ----------------
    const int n = blockIdx.x;
    const f32x4* __restrict__ row4 = (const f32x4*)(x + (size_t)n * K_DIM);

    float am = 0.f;
#pragma unroll
    for (int p = 0; p < 4; ++p) {
      f32x4 v = row4[t + 256 * p];
      am = fmaxf(am, fmaxf(fmaxf(fabsf(v[0]), fabsf(v[1])), fmaxf(fabsf(v[2]), fabsf(v[3]))));
    }
#pragma unroll
    for (int off = 32; off; off >>= 1) am = fmaxf(am, __shfl_xor(am, off, 64));
    const int wave = t >> 6, lane = t & 63;
    if (lane == 0) redf[wave] = am;
    __syncthreads();
    am = fmaxf(fmaxf(redf[0], redf[1]), fmaxf(redf[2], redf[3]));
    const float clipped = fmaxf(am, 1e-5f);
    const float qs = 127.0f / clipped;

    // thread t produces output chunk c = t (k' = 16t..16t+15):
    // word m packs k = (t>>3)*128 + 4*(t&7) + m + 32s, s=0..3
    f32x4 v[4];
#pragma unroll
    for (int s = 0; s < 4; ++s) v[s] = row4[(t >> 3) * 32 + (t & 7) + 8 * s];
    unsigned int wds[4];
    int rsum = 0;
#pragma unroll
    for (int m = 0; m < 4; ++m) {
      const int q0 = quant1(v[0][m], qs);
      const int q1 = quant1(v[1][m], qs);
      const int q2 = quant1(v[2][m], qs);
      const int q3 = quant1(v[3][m], qs);
      rsum += q0 + q1 + q2 + q3;
      wds[m] = (unsigned int)(q0 & 255) | ((unsigned int)(q1 & 255) << 8) |
               ((unsigned int)(q2 & 255) << 16) | ((unsigned int)(q3 & 255) << 24);
    }
    xq2[(size_t)t * 4096 + n] = (u32x4){wds[0], wds[1], wds[2], wds[3]};

#pragma unroll
    for (int off = 32; off; off >>= 1) rsum += __shfl_xor(rsum, off, 64);
    if (lane == 0) redi[wave] = rsum;
    __syncthreads();
    if (t == 0)
      scales[n] = make_float2(clipped * (1.0f / 127.0f),
                              (float)(redi[0] + redi[1] + redi[2] + redi[3]));
  } else {
    // ---------------- weight unpack + transpose path ----------------
    const int bid = blockIdx.x - 4096;  // 48 m-tiles x 32 kb
    const int mt = bid >> 5, kb = bid & 31;
    const int m0 = mt * 256;
    const i32x4* __restrict__ in4 = (const i32x4*)wp;
#pragma unroll 2
    for (int it = 0; it < 8; ++it) {
      const int m = m0 + it * 32 + (t >> 3);
      const i32x4 vv = in4[(size_t)m * 256 + kb * 8 + (t & 7)];  // coalesced 128-B runs
      ldsT[t >> 3][t & 7] = (u32x4){unp((unsigned int)vv[0]), unp((unsigned int)vv[1]),
                                    unp((unsigned int)vv[2]), unp((unsigned int)vv[3])};
      __syncthreads();
      wu2[(size_t)(kb * 8 + (t >> 5)) * M_DIM + m0 + it * 32 + (t & 31)] = ldsT[t & 31][t >> 5];
      __syncthreads();
    }
  }
}

// explicit inline-asm ds_read with literal offset (prevents compiler batching)
#define DSR(dst, addr, off) \
  asm volatile("ds_read_b128 %0, %1 offset:" #off : "=v"(dst) : "v"(addr))
#define LGKM(n) asm volatile("s_waitcnt lgkmcnt(" #n ")")
#define SB __builtin_amdgcn_sched_barrier(0)

#define MF(S, i, j) \
  acc[i][j] = __builtin_amdgcn_mfma_i32_32x32x32_i8(af##S[i], bf##S[j], acc[i][j], 0, 0, 0)
#define MF2(S, i) { MF(S, i, 0); MF(S, i, 1); }

// 256x256 tile, BK=128 B, 8 waves (2 row-halves x 4 col-quarters), wave-tile
// 128x64, mfma_i32_32x32x32_i8, k-chunk-major LDS (conflict-free, PMC-
// verified), R8's 2-barrier skeleton. NEW: AITER-style 1:1 MFMA<->ds_read
// instruction interleave — each quadrant's MFMA stream issues the next
// quadrant's 6 reads between MFMAs (after each register's last consumer),
// counted lgkmcnt(6) at quadrant boundaries (FIFO DS completion), lgkm(0)
// only at Q3. LDS pipe stays fed during MFMA windows regardless of wave
// phase alignment (breaks the self-synchronized read/MFMA alternation).
__global__ __launch_bounds__(512, 2) void bitgemm32(const unsigned char* __restrict__ xq2,
                                                    const unsigned char* __restrict__ wu2,
                                                    const float2* __restrict__ scales,
                                                    const float* __restrict__ wsp,
                                                    float* __restrict__ out) {
  __shared__ __align__(16) unsigned char lds[131072];  // A [2][32K] | B [2][32K]

  const int tid = threadIdx.x;
  const int l = tid & 63;
  const int w = tid >> 6;  // 0..7
  const int wm = w >> 2;   // row half 0..1
  const int wn = w & 3;    // col quarter 0..3

  // XCD swizzle: 768 blocks (%8==0 -> bijective), bm-major within each XCD
  const int cpx = gridDim.x >> 3;
  const int swz = (blockIdx.x & 7) * cpx + (blockIdx.x >> 3);
  const int bn = swz & (GN - 1);
  const int bm = swz >> 4;

  // staging: thread t writes LDS chunk-slot (q*2 + (t>>8), row t&255); source
  // chunk c = kb*8 + q*2 + (t>>8) at the same row -> contiguous 4-KiB runs.
  const unsigned char* aBase =
      xq2 + ((size_t)(tid >> 8) * 4096 + (size_t)bn * 256 + (tid & 255)) * 16;
  const unsigned char* bBase =
      wu2 + ((size_t)(tid >> 8) * 12288 + (size_t)bm * 256 + (tid & 255)) * 16;
  const int ldsDst = tid * 16;

  // fragment read base offsets: lane l -> k-half h = l>>5, row/col = l&31
  const int aFB = (l >> 5) * 4096 + (wm * 128 + (l & 31)) * 16;
  const int bFB = (l >> 5) * 4096 + (wn * 64 + (l & 31)) * 16;
  const unsigned ldsBase = (unsigned)(size_t)lds;

  i32x16 acc[4][2];
#pragma unroll
  for (int i = 0; i < 4; ++i)
#pragma unroll
    for (int j = 0; j < 2; ++j)
#pragma unroll
      for (int r = 0; r < 16; ++r) acc[i][j][r] = 0;

  auto stage = [&](int buf, int kb) {
    unsigned char* ad = lds + buf * 32768 + ldsDst;
    unsigned char* bd = lds + 65536 + buf * 32768 + ldsDst;
    const unsigned char* as_ = aBase + (size_t)kb * 524288;   // kb*8 chunks * 4096 rows
    const unsigned char* bs_ = bBase + (size_t)kb * 1572864;  // kb*8 chunks * 12288 rows
#pragma unroll
    for (int q = 0; q < 4; ++q) {
      __builtin_amdgcn_global_load_lds(
          (const __attribute__((address_space(1))) void*)(as_ + (size_t)q * 131072),
          (__attribute__((address_space(3))) void*)(ad + q * 8192), 16, 0, 0);
      __builtin_amdgcn_global_load_lds(
          (const __attribute__((address_space(1))) void*)(bs_ + (size_t)q * 393216),
          (__attribute__((address_space(3))) void*)(bd + q * 8192), 16, 0, 0);
    }
  };

  i32x4 af0[4], bf0[2], af1[4], bf1[2];

  stage(0, 0);
  for (int kb = 0; kb < NT_K; ++kb) {
    const int cur = kb & 1;
    if (kb + 1 < NT_K) {
      stage(cur ^ 1, kb + 1);
      asm volatile("s_waitcnt vmcnt(8)" ::: "memory");  // cur's 8 landed; next's in flight
    } else {
      asm volatile("s_waitcnt vmcnt(0)" ::: "memory");
    }
    __builtin_amdgcn_s_barrier();
    SB;

    const unsigned aA = ldsBase + cur * 32768 + aFB;
    const unsigned bA = ldsBase + 65536 + cur * 32768 + bFB;

    // tile prologue: Q0 -> set0, Q1 -> set1 (12 reads in flight)
    DSR(af0[0], aA, 0);    DSR(af0[1], aA, 512);  DSR(af0[2], aA, 1024); DSR(af0[3], aA, 1536);
    DSR(bf0[0], bA, 0);    DSR(bf0[1], bA, 512);
    DSR(af1[0], aA, 8192); DSR(af1[1], aA, 8704); DSR(af1[2], aA, 9216); DSR(af1[3], aA, 9728);
    DSR(bf1[0], bA, 8192); DSR(bf1[1], bA, 8704);

    // ---- Q0 (set0) : interleave Q2 reads -> set0 after last consumers ----
    LGKM(6); SB;                       // Q0 done; Q1's 6 in flight
    __builtin_amdgcn_s_setprio(1);
    MF2(0, 0); DSR(af0[0], aA, 16384);
    MF2(0, 1); DSR(af0[1], aA, 16896);
    MF2(0, 2); DSR(af0[2], aA, 17408);
    MF2(0, 3); DSR(af0[3], aA, 17920);
    DSR(bf0[0], bA, 16384); DSR(bf0[1], bA, 16896);
    __builtin_amdgcn_s_setprio(0);
    // ---- Q1 (set1) : interleave Q3 reads -> set1 ----
    LGKM(6); SB;                       // Q1 done; Q2's 6 in flight
    __builtin_amdgcn_s_setprio(1);
    MF2(1, 0); DSR(af1[0], aA, 24576);
    MF2(1, 1); DSR(af1[1], aA, 25088);
    MF2(1, 2); DSR(af1[2], aA, 25600);
    MF2(1, 3); DSR(af1[3], aA, 26112);
    DSR(bf1[0], bA, 24576); DSR(bf1[1], bA, 25088);
    __builtin_amdgcn_s_setprio(0);
    // ---- Q2 (set0) ----
    LGKM(6); SB;                       // Q2 done; Q3's 6 in flight
    __builtin_amdgcn_s_setprio(1);
    MF2(0, 0); MF2(0, 1); MF2(0, 2); MF2(0, 3);
    __builtin_amdgcn_s_setprio(0);
    // ---- Q3 (set1) ----
    LGKM(0); SB;                       // Q3 done
    __builtin_amdgcn_s_setprio(1);
    MF2(1, 0); MF2(1, 1); MF2(1, 2); MF2(1, 3);
    __builtin_amdgcn_s_setprio(0);

    __builtin_amdgcn_s_barrier();      // all reads of buf[cur] done before overwrite
  }

  // epilogue: out = (dot_codes - rowsum) * weight_scale * act_scale
  // 32x32 C/D: col = l&31, row = (r&3) + 8*(r>>2) + 4*(l>>5)
  const float wsc = wsp[0];
#pragma unroll
  for (int i = 0; i < 4; ++i) {
#pragma unroll
    for (int r = 0; r < 16; ++r) {
      const int n = bn * BM + wm * 128 + i * 32 + (r & 3) + 8 * (r >> 2) + 4 * (l >> 5);
      const float2 sc = scales[n];
      const float f = wsc * sc.x;
      float* orow = out + (size_t)n * M_DIM + bm * BN + wn * 64 + (l & 31);
#pragma unroll
      for (int j = 0; j < 2; ++j) orow[j * 32] = ((float)acc[i][j][r] - sc.y) * f;
    }
  }
}

extern "C" void kernel_launch(void* const* d_in, const int* in_sizes, int n_in,
                              void* d_out, int out_size, void* d_ws, size_t ws_size,
                              hipStream_t stream) {
  const float* x = (const float*)d_in[0];
  const int* wp = (const int*)d_in[1];
  const float* wsp = (const float*)d_in[2];
  float* out = (float*)d_out;
  const int N = in_sizes[0] / K_DIM;  // 4096 tokens

  float2* scales = (float2*)d_ws;                                  // N * 8 B
  u32x4* xq2 = (u32x4*)((char*)d_ws + 32768);                      // 16 MB, k-major
  u32x4* wu2 = (u32x4*)((char*)d_ws + 32768 + (size_t)N * K_DIM);  // 48 MB, k-major

  aux_kernel<<<4096 + 1536, 256, 0, stream>>>(x, wp, xq2, wu2, scales);
  const int grid = (N / BM) * GM;  // 768
  bitgemm32<<<grid, 512, 0, stream>>>((const unsigned char*)xq2, (const unsigned char*)wu2,
                                      scales, wsp, out);
}

// Round 13
// 231.256 us; speedup vs baseline: 1.0218x; 1.0218x over previous
//
#include <hip/hip_runtime.h>

#define K_DIM 4096
#define M_DIM 12288
#define KW 1024             // packed int32 words per weight row
#define NT_K 32             // K-tiles of 128 bytes
#define BM 256
#define BN 256
#define GN 16               // 4096/256 token tiles
#define GM 48               // 12288/256 weight tiles

typedef __attribute__((ext_vector_type(4))) int i32x4;
typedef __attribute__((ext_vector_type(16))) int i32x16;
typedef __attribute__((ext_vector_type(4))) unsigned int u32x4;
typedef __attribute__((ext_vector_type(4))) float f32x4;

__device__ __forceinline__ int quant1(float v, float qs) {
  float r = rintf(v * qs);  // round half-to-even, matches jnp.round
  r = fminf(127.f, fmaxf(-128.f, r));
  return (int)r;
}

// unpack one packed byte into 4 code bytes (0..3) at permuted positions
__device__ __forceinline__ unsigned int unp(unsigned int uv) {
  return ((uv >> 6) | (uv << 4) | (uv << 14) | (uv << 24)) & 0x03030303u;
}

// Fused aux kernel (identical to round-7..11 passing version).
__global__ __launch_bounds__(256) void aux_kernel(const float* __restrict__ x,
                                                  const int* __restrict__ wp,
                                                  u32x4* __restrict__ xq2,
                                                  u32x4* __restrict__ wu2,
                                                  float2* __restrict__ scales) {
  __shared__ float redf[4];
  __shared__ int redi[4];
  __shared__ u32x4 ldsT[32][9];  // padded: 8-lane groups conflict-free both phases
  const int t = threadIdx.x;

  if (blockIdx.x < 4096) {
    // ---------------- quant path: one block per token ----------------
    const int n = blockIdx.x;
    const f32x4* __restrict__ row4 = (const f32x4*)(x + (size_t)n * K_DIM);

    float am = 0.f;
#pragma unroll
    for (int p = 0; p < 4; ++p) {
      f32x4 v = row4[t + 256 * p];
      am = fmaxf(am, fmaxf(fmaxf(fabsf(v[0]), fabsf(v[1])), fmaxf(fabsf(v[2]), fabsf(v[3]))));
    }
#pragma unroll
    for (int off = 32; off; off >>= 1) am = fmaxf(am, __shfl_xor(am, off, 64));
    const int wave = t >> 6, lane = t & 63;
    if (lane == 0) redf[wave] = am;
    __syncthreads();
    am = fmaxf(fmaxf(redf[0], redf[1]), fmaxf(redf[2], redf[3]));
    const float clipped = fmaxf(am, 1e-5f);
    const float qs = 127.0f / clipped;

    // thread t produces output chunk c = t (k' = 16t..16t+15):
    // word m packs k = (t>>3)*128 + 4*(t&7) + m + 32s, s=0..3
    f32x4 v[4];
#pragma unroll
    for (int s = 0; s < 4; ++s) v[s] = row4[(t >> 3) * 32 + (t & 7) + 8 * s];
    unsigned int wds[4];
    int rsum = 0;
#pragma unroll
    for (int m = 0; m < 4; ++m) {
      const int q0 = quant1(v[0][m], qs);
      const int q1 = quant1(v[1][m], qs);
      const int q2 = quant1(v[2][m], qs);
      const int q3 = quant1(v[3][m], qs);
      rsum += q0 + q1 + q2 + q3;
      wds[m] = (unsigned int)(q0 & 255) | ((unsigned int)(q1 & 255) << 8) |
               ((unsigned int)(q2 & 255) << 16) | ((unsigned int)(q3 & 255) << 24);
    }
    xq2[(size_t)t * 4096 + n] = (u32x4){wds[0], wds[1], wds[2], wds[3]};

#pragma unroll
    for (int off = 32; off; off >>= 1) rsum += __shfl_xor(rsum, off, 64);
    if (lane == 0) redi[wave] = rsum;
    __syncthreads();
    if (t == 0)
      scales[n] = make_float2(clipped * (1.0f / 127.0f),
                              (float)(redi[0] + redi[1] + redi[2] + redi[3]));
  } else {
    // ---------------- weight unpack + transpose path ----------------
    const int bid = blockIdx.x - 4096;  // 48 m-tiles x 32 kb
    const int mt = bid >> 5, kb = bid & 31;
    const int m0 = mt * 256;
    const i32x4* __restrict__ in4 = (const i32x4*)wp;
#pragma unroll 2
    for (int it = 0; it < 8; ++it) {
      const int m = m0 + it * 32 + (t >> 3);
      const i32x4 vv = in4[(size_t)m * 256 + kb * 8 + (t & 7)];  // coalesced 128-B runs
      ldsT[t >> 3][t & 7] = (u32x4){unp((unsigned int)vv[0]), unp((unsigned int)vv[1]),
                                    unp((unsigned int)vv[2]), unp((unsigned int)vv[3])};
      __syncthreads();
      wu2[(size_t)(kb * 8 + (t >> 5)) * M_DIM + m0 + it * 32 + (t & 31)] = ldsT[t & 31][t >> 5];
      __syncthreads();
    }
  }
}

// explicit inline-asm ds_read with literal offset (prevents compiler batching)
#define DSR(dst, addr, off) \
  asm volatile("ds_read_b128 %0, %1 offset:" #off : "=v"(dst) : "v"(addr))
#define LGKM(n) asm volatile("s_waitcnt lgkmcnt(" #n ")")

// read the 6 fragments (4 A, 2 B) of quadrant p (literal offsets = p*8192)
#define RD_Q0 { DSR(af[0], aA, 0);     DSR(af[1], aA, 512);   DSR(af[2], aA, 1024);  DSR(af[3], aA, 1536);  DSR(bf[0], bA, 0);     DSR(bf[1], bA, 512);   }
#define RD_Q1 { DSR(af[0], aA, 8192);  DSR(af[1], aA, 8704);  DSR(af[2], aA, 9216);  DSR(af[3], aA, 9728);  DSR(bf[0], bA, 8192);  DSR(bf[1], bA, 8704);  }
#define RD_Q2 { DSR(af[0], aA, 16384); DSR(af[1], aA, 16896); DSR(af[2], aA, 17408); DSR(af[3], aA, 17920); DSR(bf[0], bA, 16384); DSR(bf[1], bA, 16896); }
#define RD_Q3 { DSR(af[0], aA, 24576); DSR(af[1], aA, 25088); DSR(af[2], aA, 25600); DSR(af[3], aA, 26112); DSR(bf[0], bA, 24576); DSR(bf[1], bA, 25088); }

#define MFMA8                                                                          \
  {                                                                                    \
    __builtin_amdgcn_s_setprio(1);                                                     \
    _Pragma("unroll") for (int i_ = 0; i_ < 4; ++i_)                                   \
        _Pragma("unroll") for (int j_ = 0; j_ < 2; ++j_) acc[i_][j_] =                 \
            __builtin_amdgcn_mfma_i32_32x32x32_i8(af[i_], bf[j_], acc[i_][j_],         \
                                                  0, 0, 0);                            \
    __builtin_amdgcn_s_setprio(0);                                                     \
  }

// phase 0: VALIDATED entry — stage next pair, counted vmcnt (tile kb's 8
// landed, next tile's 2 in flight), barrier, THEN read buf[cur].
#define PHASE0(STG, WAITC)               \
  {                                      \
    STG;                                 \
    WAITC;                               \
    __builtin_amdgcn_s_barrier();        \
    __builtin_amdgcn_sched_barrier(0);   \
    RD_Q0;                               \
    LGKM(0);                             \
    __builtin_amdgcn_sched_barrier(0);   \
    MFMA8;                               \
    __builtin_amdgcn_s_barrier();        \
  }

// phases 1-3: m201 read-hiding form — reads (of the already-validated buf)
// + stage pair BEFORE barrier (barrier wait hides read latency), lgkm(0)
// after, MFMA cluster, trailing barrier.
#define PHASE(RD, STG)                   \
  {                                      \
    RD;                                  \
    STG;                                 \
    __builtin_amdgcn_s_barrier();        \
    LGKM(0);                             \
    __builtin_amdgcn_sched_barrier(0);   \
    MFMA8;                               \
    __builtin_amdgcn_s_barrier();        \
  }

// 256x256 tile, BK=128 B, 8 waves (2 row-halves x 4 col-quarters), wave-tile
// 128x64, mfma_i32_32x32x32_i8, k-chunk-major LDS (conflict-free, PMC-
// verified). 8-barrier/tile m201 schedule with race-free phase 0; stage
// split 2-loads/phase; single counted vmcnt(2) per tile (never 0 mid-loop).
// XCD block swizzle. BEST MEASURED: 229.6 us total (round 11).
__global__ __launch_bounds__(512, 2) void bitgemm32(const unsigned char* __restrict__ xq2,
                                                    const unsigned char* __restrict__ wu2,
                                                    const float2* __restrict__ scales,
                                                    const float* __restrict__ wsp,
                                                    float* __restrict__ out) {
  __shared__ __align__(16) unsigned char lds[131072];  // A [2][32K] | B [2][32K]

  const int tid = threadIdx.x;
  const int l = tid & 63;
  const int w = tid >> 6;  // 0..7
  const int wm = w >> 2;   // row half 0..1
  const int wn = w & 3;    // col quarter 0..3

  // XCD swizzle: 768 blocks (%8==0 -> bijective), bm-major within each XCD
  const int cpx = gridDim.x >> 3;
  const int swz = (blockIdx.x & 7) * cpx + (blockIdx.x >> 3);
  const int bn = swz & (GN - 1);
  const int bm = swz >> 4;

  // staging: thread t writes LDS chunk-slot (q*2 + (t>>8), row t&255); source
  // chunk c = kb*8 + q*2 + (t>>8) at the same row -> contiguous 4-KiB runs.
  const unsigned char* aBase =
      xq2 + ((size_t)(tid >> 8) * 4096 + (size_t)bn * 256 + (tid & 255)) * 16;
  const unsigned char* bBase =
      wu2 + ((size_t)(tid >> 8) * 12288 + (size_t)bm * 256 + (tid & 255)) * 16;
  const int ldsDst = tid * 16;

  // fragment read base offsets: lane l -> k-half h = l>>5, row/col = l&31
  const int aFB = (l >> 5) * 4096 + (wm * 128 + (l & 31)) * 16;
  const int bFB = (l >> 5) * 4096 + (wn * 64 + (l & 31)) * 16;
  const unsigned ldsBase = (unsigned)(size_t)lds;

  i32x16 acc[4][2];
#pragma unroll
  for (int i = 0; i < 4; ++i)
#pragma unroll
    for (int j = 0; j < 2; ++j)
#pragma unroll
      for (int r = 0; r < 16; ++r) acc[i][j][r] = 0;

  // stage quarter q of tile kb into buffer buf (2 gloads: 1 A + 1 B)
  auto stageQ = [&](int buf, int kb, int q) {
    __builtin_amdgcn_global_load_lds(
        (const __attribute__((address_space(1))) void*)(aBase + (size_t)kb * 524288 +
                                                        (size_t)q * 131072),
        (__attribute__((address_space(3))) void*)(lds + buf * 32768 + ldsDst + q * 8192), 16, 0,
        0);
    __builtin_amdgcn_global_load_lds(
        (const __attribute__((address_space(1))) void*)(bBase + (size_t)kb * 1572864 +
                                                        (size_t)q * 393216),
        (__attribute__((address_space(3))) void*)(lds + 65536 + buf * 32768 + ldsDst + q * 8192),
        16, 0, 0);
  };

  i32x4 af[4], bf[2];

  // prologue: stage all of tile 0
#pragma unroll
  for (int q = 0; q < 4; ++q) stageQ(0, 0, q);

  for (int kb = 0; kb < NT_K; ++kb) {
    const int cur = kb & 1;
    const int nbuf = cur ^ 1;
    const bool pf = (kb + 1 < NT_K);
    const unsigned aA = ldsBase + cur * 32768 + aFB;
    const unsigned bA = ldsBase + 65536 + cur * 32768 + bFB;

    if (pf) {
      PHASE0(stageQ(nbuf, kb + 1, 0), asm volatile("s_waitcnt vmcnt(2)" ::: "memory"));
      PHASE(RD_Q1, stageQ(nbuf, kb + 1, 1));
      PHASE(RD_Q2, stageQ(nbuf, kb + 1, 2));
      PHASE(RD_Q3, stageQ(nbuf, kb + 1, 3));
    } else {
      PHASE0(, asm volatile("s_waitcnt vmcnt(0)" ::: "memory"));
      PHASE(RD_Q1, );
      PHASE(RD_Q2, );
      PHASE(RD_Q3, );
    }
  }

  // epilogue: out = (dot_codes - rowsum) * weight_scale * act_scale
  // 32x32 C/D: col = l&31, row = (r&3) + 8*(r>>2) + 4*(l>>5)
  const float wsc = wsp[0];
#pragma unroll
  for (int i = 0; i < 4; ++i) {
#pragma unroll
    for (int r = 0; r < 16; ++r) {
      const int n = bn * BM + wm * 128 + i * 32 + (r & 3) + 8 * (r >> 2) + 4 * (l >> 5);
      const float2 sc = scales[n];
      const float f = wsc * sc.x;
      float* orow = out + (size_t)n * M_DIM + bm * BN + wn * 64 + (l & 31);
#pragma unroll
      for (int j = 0; j < 2; ++j) orow[j * 32] = ((float)acc[i][j][r] - sc.y) * f;
    }
  }
}

extern "C" void kernel_launch(void* const* d_in, const int* in_sizes, int n_in,
                              void* d_out, int out_size, void* d_ws, size_t ws_size,
                              hipStream_t stream) {
  const float* x = (const float*)d_in[0];
  const int* wp = (const int*)d_in[1];
  const float* wsp = (const float*)d_in[2];
  float* out = (float*)d_out;
  const int N = in_sizes[0] / K_DIM;  // 4096 tokens

  float2* scales = (float2*)d_ws;                                  // N * 8 B
  u32x4* xq2 = (u32x4*)((char*)d_ws + 32768);                      // 16 MB, k-major
  u32x4* wu2 = (u32x4*)((char*)d_ws + 32768 + (size_t)N * K_DIM);  // 48 MB, k-major

  aux_kernel<<<4096 + 1536, 256, 0, stream>>>(x, wp, xq2, wu2, scales);
  const int grid = (N / BM) * GM;  // 768
  bitgemm32<<<grid, 512, 0, stream>>>((const unsigned char*)xq2, (const unsigned char*)wu2,
                                      scales, wsp, out);
}